// Round 2
// baseline (659.471 us; speedup 1.0000x reference)
//
#include <hip/hip_runtime.h>
#include <math.h>

#define BB 32     // batch
#define TT 64     // time steps
#define VV 32000  // vocab
#define HH 32     // hidden
#define EE 200    // embedding dim
#define VC 25     // vocab chunks for the stats pass
#define CHUNK 1280        // VV / VC
#define TILE 256          // v-rows staged in LDS at a time
#define NTILE 5           // CHUNK / TILE
#define WPAD 33           // padded LDS row stride (floats): bank=(r+e)%32 -> 2-way (free)
#define WVT 125   // k_write v-tiles: VV / 256

// ---------------- Kernel 1: i2h = emb_table[y] @ Wi.T + bi + bh ----------------
__global__ void k_i2h(const int* __restrict__ y, const float* __restrict__ emb,
                      const float* __restrict__ Wi, const float* __restrict__ bi,
                      const float* __restrict__ bh, float* __restrict__ i2h) {
    int bt = blockIdx.x;              // 0..2047  (= b*TT + t)
    int tok = y[bt];
    __shared__ float se[EE];
    for (int e = threadIdx.x; e < EE; e += blockDim.x) se[e] = emb[(size_t)tok * EE + e];
    __syncthreads();
    int h = threadIdx.x >> 3;         // 0..31
    int j = threadIdx.x & 7;          // 8 lanes per h
    float acc = 0.f;
    for (int e = j; e < EE; e += 8) acc += se[e] * Wi[h * EE + e];
    acc += __shfl_down(acc, 4, 8);
    acc += __shfl_down(acc, 2, 8);
    acc += __shfl_down(acc, 1, 8);
    if (j == 0) i2h[bt * HH + h] = acc + bi[h] + bh[h];
}

// ---------------- Kernel 2: recurrence h_t = tanh(i2h_t + h_{t-1} @ Wh.T) ------
__global__ void k_rnn(const float* __restrict__ enc, const float* __restrict__ Wh,
                      const float* __restrict__ i2h, float* __restrict__ hall) {
    int b = blockIdx.x;               // 0..31
    int tid = threadIdx.x;            // 64 threads = 1 wave
    __shared__ float hs[HH];
    __shared__ float sWh[HH][HH + 1]; // +1 pad: breaks 32-way bank conflict on row reads
    __shared__ float si[TT * HH];     // all i2h for this b (8 KB)
    for (int i = tid; i < HH * HH; i += 64) sWh[i >> 5][i & 31] = Wh[i];
    for (int i = tid; i < TT * HH; i += 64) si[i] = i2h[b * TT * HH + i];
    if (tid < HH) hs[tid] = enc[b * HH + tid];
    __syncthreads();
    for (int t = 0; t < TT; ++t) {
        float hv = 0.f;
        if (tid < HH) {
            float a0 = si[t * HH + tid], a1 = 0.f, a2 = 0.f, a3 = 0.f;
#pragma unroll
            for (int j = 0; j < HH; j += 4) {
                a0 += sWh[tid][j]     * hs[j];
                a1 += sWh[tid][j + 1] * hs[j + 1];
                a2 += sWh[tid][j + 2] * hs[j + 2];
                a3 += sWh[tid][j + 3] * hs[j + 3];
            }
            hv = tanhf((a0 + a1) + (a2 + a3));
        }
        __syncthreads();
        if (tid < HH) {
            hs[tid] = hv;
            hall[(b * TT + t) * HH + tid] = hv;
        }
        __syncthreads();
    }
}

// ---------------- Kernel 3: per-chunk stats (max, argmax, sum of exp) ----------
// grid = (VC=25, TT), block = 256 = 4 waves; wave w owns b in [8w,8w+8).
// Wo is staged per 256-row tile into LDS with COALESCED float4 loads (the old
// direct loads strode 128 B across lanes = 64 cache lines / instr -> TA-bound).
// LDS rows padded to 33 floats: read bank = (row+e)%32 -> 2-way alias = free.
// Each lane processes rows {l, l+64} then {l+128, l+192}: 2 rows per h-broadcast
// halves the CU-shared LDS-pipe traffic. |logit| < 6 so exp() without
// max-subtraction is safe; partial sums add directly.
__global__ __launch_bounds__(256) void k_stats(
        const float* __restrict__ Wo, const float* __restrict__ bo,
        const float* __restrict__ hall,
        float* __restrict__ pmax, float* __restrict__ pamx, float* __restrict__ psum) {
    int t = blockIdx.y;
    int c = blockIdx.x;
    int v0 = c * CHUNK;
    int wv = threadIdx.x >> 6;        // wave id 0..3 -> b-group
    int l  = threadIdx.x & 63;        // lane in wave
    int b0 = wv * 8;
    __shared__ __align__(16) float shs[BB][HH];   // 4 KB
    __shared__ float sw[TILE * WPAD];             // 33792 B
    for (int i = threadIdx.x; i < BB * HH; i += 256) {
        int b = i >> 5, k = i & 31;
        shs[b][k] = hall[(b * TT + t) * HH + k];
    }

    float mx[8], am[8], sm[8];
#pragma unroll
    for (int j = 0; j < 8; ++j) { mx[j] = -1e30f; am[j] = 0.f; sm[j] = 0.f; }

    for (int tile = 0; tile < NTILE; ++tile) {
        int tv0 = v0 + tile * TILE;
        __syncthreads();              // previous tile's compute done (no-op on tile 0)
        // ---- stage: 256 rows x 32 floats; 8 coalesced float4 loads / thread ----
#pragma unroll
        for (int k = 0; k < 8; ++k) {
            int m = k * 256 + (int)threadIdx.x;   // 16B-chunk index 0..2047
            int row = m >> 3, q = m & 7;
            float4 d = *(const float4*)(Wo + (size_t)(tv0 + row) * HH + q * 4);
            float* dst = &sw[row * WPAD + q * 4]; // 4B-aligned only -> scalar stores
            dst[0] = d.x; dst[1] = d.y; dst[2] = d.z; dst[3] = d.w;
        }
        __syncthreads();              // staging (and shs on tile 0) visible

        // ---- compute: 2 row-groups of 2 rows each ----
#pragma unroll
        for (int g = 0; g < 2; ++g) {
            int r0 = l + g * 128;                 // rows r0 and r0+64
            float wr0[32], wr1[32];
#pragma unroll
            for (int e = 0; e < 32; ++e) {        // padded reads: 2-way = free
                wr0[e] = sw[r0 * WPAD + e];
                wr1[e] = sw[(r0 + 64) * WPAD + e];
            }
            float bo0 = bo[tv0 + r0], bo1 = bo[tv0 + r0 + 64];
            float vf0 = (float)(tv0 + r0), vf1 = vf0 + 64.f;
#pragma unroll
            for (int j = 0; j < 8; ++j) {
                const float4* hb = (const float4*)&shs[b0 + j][0];  // broadcast
                float acc0 = bo0, acc1 = bo1;
#pragma unroll
                for (int q = 0; q < 8; ++q) {
                    float4 hq = hb[q];
                    acc0 += hq.x * wr0[4*q] + hq.y * wr0[4*q+1] + hq.z * wr0[4*q+2] + hq.w * wr0[4*q+3];
                    acc1 += hq.x * wr1[4*q] + hq.y * wr1[4*q+1] + hq.z * wr1[4*q+2] + hq.w * wr1[4*q+3];
                }
                sm[j] += __expf(acc0);
                if (acc0 > mx[j]) { mx[j] = acc0; am[j] = vf0; }   // lower v first:
                sm[j] += __expf(acc1);                              // ties keep low idx
                if (acc1 > mx[j]) { mx[j] = acc1; am[j] = vf1; }
            }
        }
    }

    // per-wave butterfly reduce (64 lanes); first-occurrence tie -> smaller index
#pragma unroll
    for (int j = 0; j < 8; ++j) {
#pragma unroll
        for (int off = 32; off > 0; off >>= 1) {
            float m2 = __shfl_down(mx[j], off);
            float a2 = __shfl_down(am[j], off);
            float s2 = __shfl_down(sm[j], off);
            sm[j] += s2;
            if (m2 > mx[j] || (m2 == mx[j] && a2 < am[j])) { mx[j] = m2; am[j] = a2; }
        }
    }
    if (l == 0) {   // b-groups are disjoint: no cross-wave reduction needed
        int base = (t * VC + c) * BB + b0;
#pragma unroll
        for (int j = 0; j < 8; ++j) {
            pmax[base + j] = mx[j];
            pamx[base + j] = am[j];
            psum[base + j] = sm[j];
        }
    }
}

// ---------------- Kernel 4: combine partials -> lse, preds ---------------------
__global__ void k_combine(const float* __restrict__ pmax, const float* __restrict__ pamx,
                          const float* __restrict__ psum,
                          float* __restrict__ lse, float* __restrict__ preds) {
    int r = blockIdx.x * blockDim.x + threadIdx.x;   // r = b*TT + t
    if (r >= BB * TT) return;
    int b = r >> 6, t = r & 63;
    float m = -1e30f, a = 0.f, s = 0.f;
    for (int c = 0; c < VC; ++c) {
        int idx = (t * VC + c) * BB + b;
        float m2 = pmax[idx], a2 = pamx[idx];
        s += psum[idx];
        if (m2 > m || (m2 == m && a2 < a)) { m = m2; a = a2; }
    }
    lse[r] = logf(s);
    preds[r] = a;    // preds[b][t], index value as float (exact up to 2^24)
}

// ---------------- Kernel 5: recompute logits, write logp -----------------------
// grid (125, 64), block 256; one thread per vocab row. Wo staged to padded LDS
// with coalesced loads (same fix as k_stats), w-row held in 32 VGPRs, h read as
// wave-uniform float4 broadcasts. Roofline: the 262 MB output write.
__global__ __launch_bounds__(256) void k_write(
        const float* __restrict__ Wo, const float* __restrict__ bo,
        const float* __restrict__ hall, const float* __restrict__ lse,
        float* __restrict__ out) {
    int t = blockIdx.y;
    int v0 = blockIdx.x * 256;
    __shared__ __align__(16) float shs[BB][HH];
    __shared__ float sl[BB];
    __shared__ float sw[TILE * WPAD];
    for (int i = threadIdx.x; i < BB * HH; i += 256) {
        int b = i >> 5, k = i & 31;
        shs[b][k] = hall[(b * TT + t) * HH + k];
    }
    if (threadIdx.x < BB) sl[threadIdx.x] = lse[threadIdx.x * TT + t];
#pragma unroll
    for (int k = 0; k < 8; ++k) {
        int m = k * 256 + (int)threadIdx.x;
        int row = m >> 3, q = m & 7;
        float4 d = *(const float4*)(Wo + (size_t)(v0 + row) * HH + q * 4);
        float* dst = &sw[row * WPAD + q * 4];
        dst[0] = d.x; dst[1] = d.y; dst[2] = d.z; dst[3] = d.w;
    }
    __syncthreads();

    int r = threadIdx.x;              // this thread's vocab row within the tile
    float w[32];
#pragma unroll
    for (int e = 0; e < 32; ++e) w[e] = sw[r * WPAD + e];   // 2-way = free
    float bov = bo[v0 + r];
    size_t obase = (size_t)t * VV + v0 + r;
#pragma unroll
    for (int b = 0; b < BB; ++b) {
        const float4* hb = (const float4*)&shs[b][0];   // broadcast
        float acc = bov - sl[b];
#pragma unroll
        for (int q = 0; q < 8; ++q) {
            float4 hq = hb[q];
            acc += hq.x * w[4*q] + hq.y * w[4*q+1] + hq.z * w[4*q+2] + hq.w * w[4*q+3];
        }
        out[(size_t)b * TT * VV + obase] = acc;
    }
}

// ---------------- Launch -------------------------------------------------------
extern "C" void kernel_launch(void* const* d_in, const int* in_sizes, int n_in,
                              void* d_out, int out_size, void* d_ws, size_t ws_size,
                              hipStream_t stream) {
    const int*   y   = (const int*)  d_in[0];
    const float* enc = (const float*)d_in[1];
    const float* emb = (const float*)d_in[2];
    const float* Wi  = (const float*)d_in[3];
    const float* bi  = (const float*)d_in[4];
    const float* Wh  = (const float*)d_in[5];
    const float* bh  = (const float*)d_in[6];
    const float* Wo  = (const float*)d_in[7];
    const float* bo  = (const float*)d_in[8];
    float* out = (float*)d_out;
    float* ws  = (float*)d_ws;

    // workspace layout (floats)
    float* i2h  = ws;                   // 65536
    float* hall = ws + 65536;           // 65536
    float* pmax = ws + 131072;          // TT*VC*BB = 51200
    float* pamx = ws + 182272;          // 51200
    float* psum = ws + 233472;          // 51200
    float* lse  = ws + 284672;          // 2048

    k_i2h<<<BB * TT, 256, 0, stream>>>(y, emb, Wi, bi, bh, i2h);
    k_rnn<<<BB, 64, 0, stream>>>(enc, Wh, i2h, hall);
    dim3 gs(VC, TT);
    k_stats<<<gs, 256, 0, stream>>>(Wo, bo, hall, pmax, pamx, psum);
    k_combine<<<(BB * TT + 255) / 256, 256, 0, stream>>>(pmax, pamx, psum, lse,
                                                         out + (size_t)BB * TT * VV);
    dim3 gw(WVT, TT);
    k_write<<<gw, 256, 0, stream>>>(Wo, bo, hall, lse, out);
}

// Round 4
// 465.275 us; speedup vs baseline: 1.4174x; 1.4174x over previous
//
#include <hip/hip_runtime.h>
#include <math.h>

#define BB 32     // batch
#define TT 64     // time steps
#define VV 32000  // vocab
#define HH 32     // hidden
#define EE 200    // embedding dim
#define MM (BB * TT)      // 2048 GEMM rows (r = b*TT + t)
#define MTILES (MM / 16)  // 128
#define VC 16             // stats v-chunks (partials sized to fit 1.3 MB ws)
#define VTPC 125          // 16-col v-tiles per chunk (2000 cols)
#define NWE (VV * HH)     // Wo element count

typedef __attribute__((ext_vector_type(8))) short short8;   // 8 bf16 = 4 VGPR
typedef __attribute__((ext_vector_type(4))) float f32x4;

// x = l0 + l1 + l2 with li bf16 (RNE): combined ~26 mantissa bits >= f32's 24.
__device__ inline void split3(float x, ushort& u0, ushort& u1, ushort& u2) {
    unsigned a = __float_as_uint(x);
    ushort t0 = (ushort)((a + 0x7FFFu + ((a >> 16) & 1u)) >> 16);
    float f0 = __uint_as_float(((unsigned)t0) << 16);
    float r1 = x - f0;
    unsigned b = __float_as_uint(r1);
    ushort t1 = (ushort)((b + 0x7FFFu + ((b >> 16) & 1u)) >> 16);
    float f1 = __uint_as_float(((unsigned)t1) << 16);
    float r2 = r1 - f1;
    unsigned c = __float_as_uint(r2);
    ushort t2 = (ushort)((c + 0x7FFFu + ((c >> 16) & 1u)) >> 16);
    u0 = t0; u1 = t1; u2 = t2;
}

// 6-product bf16x3 MFMA: a*b to ~1e-7 relative. Small terms first.
__device__ inline f32x4 mfma6(short8 a0, short8 a1, short8 a2,
                              short8 b0, short8 b1, short8 b2) {
    f32x4 acc = {0.f, 0.f, 0.f, 0.f};
    acc = __builtin_amdgcn_mfma_f32_16x16x32_bf16(a2, b0, acc, 0, 0, 0);
    acc = __builtin_amdgcn_mfma_f32_16x16x32_bf16(a0, b2, acc, 0, 0, 0);
    acc = __builtin_amdgcn_mfma_f32_16x16x32_bf16(a1, b1, acc, 0, 0, 0);
    acc = __builtin_amdgcn_mfma_f32_16x16x32_bf16(a1, b0, acc, 0, 0, 0);
    acc = __builtin_amdgcn_mfma_f32_16x16x32_bf16(a0, b1, acc, 0, 0, 0);
    acc = __builtin_amdgcn_mfma_f32_16x16x32_bf16(a0, b0, acc, 0, 0, 0);
    return acc;
}

// ---------------- Kernel 1: i2h = emb_table[y] @ Wi.T + bi + bh ----------------
__global__ void k_i2h(const int* __restrict__ y, const float* __restrict__ emb,
                      const float* __restrict__ Wi, const float* __restrict__ bi,
                      const float* __restrict__ bh, float* __restrict__ i2h) {
    int bt = blockIdx.x;              // 0..2047  (= b*TT + t)
    int tok = y[bt];
    __shared__ float se[EE];
    for (int e = threadIdx.x; e < EE; e += blockDim.x) se[e] = emb[(size_t)tok * EE + e];
    __syncthreads();
    int h = threadIdx.x >> 3;         // 0..31
    int j = threadIdx.x & 7;          // 8 lanes per h
    float acc = 0.f;
    for (int e = j; e < EE; e += 8) acc += se[e] * Wi[h * EE + e];
    acc += __shfl_down(acc, 4, 8);
    acc += __shfl_down(acc, 2, 8);
    acc += __shfl_down(acc, 1, 8);
    if (j == 0) i2h[bt * HH + h] = acc + bi[h] + bh[h];
}

// ---------------- Kernel 2: recurrence h_t = tanh(i2h_t + h_{t-1} @ Wh.T) ------
__global__ void k_rnn(const float* __restrict__ enc, const float* __restrict__ Wh,
                      const float* __restrict__ i2h, float* __restrict__ hall) {
    int b = blockIdx.x;               // 0..31
    int tid = threadIdx.x;            // 64 threads = 1 wave
    __shared__ float hs[HH];
    __shared__ float sWh[HH][HH + 1];
    __shared__ float si[TT * HH];
    for (int i = tid; i < HH * HH; i += 64) sWh[i >> 5][i & 31] = Wh[i];
    for (int i = tid; i < TT * HH; i += 64) si[i] = i2h[b * TT * HH + i];
    if (tid < HH) hs[tid] = enc[b * HH + tid];
    __syncthreads();
    for (int t = 0; t < TT; ++t) {
        float hv = 0.f;
        if (tid < HH) {
            float a0 = si[t * HH + tid], a1 = 0.f, a2 = 0.f, a3 = 0.f;
#pragma unroll
            for (int j = 0; j < HH; j += 4) {
                a0 += sWh[tid][j]     * hs[j];
                a1 += sWh[tid][j + 1] * hs[j + 1];
                a2 += sWh[tid][j + 2] * hs[j + 2];
                a3 += sWh[tid][j + 3] * hs[j + 3];
            }
            hv = tanhf((a0 + a1) + (a2 + a3));
        }
        __syncthreads();
        if (tid < HH) {
            hs[tid] = hv;
            hall[(b * TT + t) * HH + tid] = hv;
        }
        __syncthreads();
    }
}

// ---------------- Kernel 2.5: limb split. W limbs -> out region (scratch), -----
// H limbs -> workspace. out[0..6.1MB) is scribble space until k_write overwrites.
__global__ void k_limbs(const float* __restrict__ Wo, const float* __restrict__ hall,
                        ushort* __restrict__ W0, ushort* __restrict__ W1, ushort* __restrict__ W2,
                        ushort* __restrict__ H0, ushort* __restrict__ H1, ushort* __restrict__ H2) {
    int i = blockIdx.x * 256 + threadIdx.x;
    if (i < NWE) {
        ushort u0, u1, u2; split3(Wo[i], u0, u1, u2);
        W0[i] = u0; W1[i] = u1; W2[i] = u2;
    } else {
        int j = i - NWE;
        if (j >= MM * HH) return;
        ushort u0, u1, u2; split3(hall[j], u0, u1, u2);
        H0[j] = u0; H1[j] = u1; H2[j] = u2;
    }
}

// ---------------- Kernel 3: stats via MFMA -------------------------------------
// grid (VC=16, 32), 256 thr = 4 independent waves (no barriers); wave w owns
// M-tile blockIdx.y*4+w. All 4 waves stream the same W-limb tiles -> L1 dedup.
// C/D layout [m89]: col=lane&15 (v), row=(lane>>4)*4+q (m). Stats in 12 VGPRs.
__global__ __launch_bounds__(256) void k_stats_mfma(
        const ushort* __restrict__ W0, const ushort* __restrict__ W1, const ushort* __restrict__ W2,
        const ushort* __restrict__ H0, const ushort* __restrict__ H1, const ushort* __restrict__ H2,
        const float* __restrict__ bo,
        float* __restrict__ pmax, float* __restrict__ pamx, float* __restrict__ psum) {
    int c  = blockIdx.x;
    int wv = threadIdx.x >> 6;
    int l  = threadIdx.x & 63;
    int lc = l & 15, lg = l >> 4;
    int m0 = (blockIdx.y * 4 + wv) * 16;
    size_t aoff = (size_t)(m0 + lc) * HH + lg * 8;
    short8 a0 = *(const short8*)(H0 + aoff);
    short8 a1 = *(const short8*)(H1 + aoff);
    short8 a2 = *(const short8*)(H2 + aoff);

    float mx[4], am[4], sm[4];
#pragma unroll
    for (int q = 0; q < 4; ++q) { mx[q] = -1e30f; am[q] = 0.f; sm[q] = 0.f; }

    int vb = c * (VTPC * 16);         // chunk base column
#pragma unroll 5
    for (int s = 0; s < VTPC; ++s) {
        int v = vb + s * 16 + lc;     // this lane's vocab row in tile s
        size_t boff = (size_t)v * HH + lg * 8;
        short8 b0 = *(const short8*)(W0 + boff);
        short8 b1 = *(const short8*)(W1 + boff);
        short8 b2 = *(const short8*)(W2 + boff);
        f32x4 acc = mfma6(a0, a1, a2, b0, b1, b2);
        float bov = bo[v];
        float vf  = (float)v;
#pragma unroll
        for (int q = 0; q < 4; ++q) {
            float g = acc[q] + bov;
            sm[q] += __expf(g);       // |logit| < ~6: exp w/o max-shift is safe
            if (g > mx[q]) { mx[q] = g; am[q] = vf; }   // strict >: first-occurrence
        }
    }

    // reduce across the 16 lanes (lc bits) sharing the same 4 rows
#pragma unroll
    for (int q = 0; q < 4; ++q) {
#pragma unroll
        for (int msk = 1; msk <= 8; msk <<= 1) {
            float m2 = __shfl_xor(mx[q], msk);
            float av = __shfl_xor(am[q], msk);
            float s2 = __shfl_xor(sm[q], msk);
            sm[q] += s2;
            if (m2 > mx[q] || (m2 == mx[q] && av < am[q])) { mx[q] = m2; am[q] = av; }
        }
    }
    if (lc == 0) {
        int base = c * MM + m0 + lg * 4;
#pragma unroll
        for (int q = 0; q < 4; ++q) {
            pmax[base + q] = mx[q];
            pamx[base + q] = am[q];
            psum[base + q] = sm[q];
        }
    }
}

// ---------------- Kernel 4: combine partials -> lse, preds ---------------------
__global__ void k_combine(const float* __restrict__ pmax, const float* __restrict__ pamx,
                          const float* __restrict__ psum,
                          float* __restrict__ lse, float* __restrict__ preds) {
    int r = blockIdx.x * blockDim.x + threadIdx.x;   // r = b*TT + t
    if (r >= MM) return;
    float m = -1e30f, a = 0.f, s = 0.f;
    for (int c = 0; c < VC; ++c) {
        int idx = c * MM + r;
        float m2 = pmax[idx], a2 = pamx[idx];
        s += psum[idx];
        if (m2 > m || (m2 == m && a2 < a)) { m = m2; a = a2; }
    }
    lse[r] = logf(s);
    preds[r] = a;    // preds[b][t] (r = b*TT+t), index as float (exact to 2^24)
}

// ---------------- Kernel 5: logits via MFMA, on-the-fly W conversion -----------
// grid (1000, 2), 1 wave. Block owns 32 vocab cols: converts those 32 Wo rows to
// limb frags ONCE in registers (no dependence on the out-region limbs -> no race
// with overwriting them), then loops 64 M-tiles. Same split3+mfma6 as stats =>
// bit-identical logits. Stores: 4 x 64-B segments / instr. Roofline: 262 MB write.
__global__ __launch_bounds__(64) void k_write_conv(
        const float* __restrict__ Wo,
        const ushort* __restrict__ H0, const ushort* __restrict__ H1, const ushort* __restrict__ H2,
        const float* __restrict__ bo, const float* __restrict__ lse,
        float* __restrict__ out) {
    int v0 = blockIdx.x * 32;
    int lc = threadIdx.x & 15, lg = threadIdx.x >> 4;

    short8 b0a, b1a, b2a, b0b, b1b, b2b;
    {
        const float* ra = Wo + (size_t)(v0 + lc) * HH + lg * 8;
        const float* rb = ra + 16 * HH;
#pragma unroll
        for (int j = 0; j < 8; ++j) {
            ushort u0, u1, u2; split3(ra[j], u0, u1, u2);
            b0a[j] = (short)u0; b1a[j] = (short)u1; b2a[j] = (short)u2;
        }
#pragma unroll
        for (int j = 0; j < 8; ++j) {
            ushort u0, u1, u2; split3(rb[j], u0, u1, u2);
            b0b[j] = (short)u0; b1b[j] = (short)u1; b2b[j] = (short)u2;
        }
    }
    float boA = bo[v0 + lc], boB = bo[v0 + 16 + lc];

    int mbase = blockIdx.y * (MM / 2);
    for (int s = 0; s < MM / 2 / 16; ++s) {
        int m0 = mbase + s * 16;
        size_t aoff = (size_t)(m0 + lc) * HH + lg * 8;
        short8 a0 = *(const short8*)(H0 + aoff);
        short8 a1 = *(const short8*)(H1 + aoff);
        short8 a2 = *(const short8*)(H2 + aoff);
        f32x4 accA = mfma6(a0, a1, a2, b0a, b1a, b2a);
        f32x4 accB = mfma6(a0, a1, a2, b0b, b1b, b2b);
        int row = m0 + lg * 4;
#pragma unroll
        for (int q = 0; q < 4; ++q) {
            float ls = lse[row + q];
            size_t ob = (size_t)(row + q) * VV + v0 + lc;
            out[ob]      = accA[q] + boA - ls;
            out[ob + 16] = accB[q] + boB - ls;
        }
    }
}

// ---------------- Launch -------------------------------------------------------
extern "C" void kernel_launch(void* const* d_in, const int* in_sizes, int n_in,
                              void* d_out, int out_size, void* d_ws, size_t ws_size,
                              hipStream_t stream) {
    const int*   y   = (const int*)  d_in[0];
    const float* enc = (const float*)d_in[1];
    const float* emb = (const float*)d_in[2];
    const float* Wi  = (const float*)d_in[3];
    const float* bi  = (const float*)d_in[4];
    const float* Wh  = (const float*)d_in[5];
    const float* bh  = (const float*)d_in[6];
    const float* Wo  = (const float*)d_in[7];
    const float* bo  = (const float*)d_in[8];
    float* out = (float*)d_out;
    float* ws  = (float*)d_ws;

    // workspace (floats) — total 329,728 floats = 1.319 MB, same as round 0/1.
    float* i2h  = ws;                   // 65536
    float* hall = ws + 65536;           // 65536
    float* pmax = ws + 131072;          // VC*MM = 32768
    float* pamx = ws + 163840;          // 32768
    float* psum = ws + 196608;          // 32768
    float* lse  = ws + 229376;          // 2048
    ushort* Hu  = (ushort*)(ws + 231424);   // 3 * 65536 ushorts = 98304 floats
    ushort* H0 = Hu, *H1 = H0 + MM * HH, *H2 = H1 + MM * HH;

    // W limbs: scratch inside the (not-yet-written) logprobs output region.
    ushort* Wu = (ushort*)out;              // 3 * 1,024,000 ushorts = 6.1 MB
    ushort* W0 = Wu, *W1 = W0 + NWE, *W2 = W1 + NWE;

    k_i2h<<<MM, 256, 0, stream>>>(y, emb, Wi, bi, bh, i2h);
    k_rnn<<<BB, 64, 0, stream>>>(enc, Wh, i2h, hall);
    int tot = NWE + MM * HH;
    k_limbs<<<(tot + 255) / 256, 256, 0, stream>>>(Wo, hall, W0, W1, W2, H0, H1, H2);
    dim3 gs(VC, 32);
    k_stats_mfma<<<gs, 256, 0, stream>>>(W0, W1, W2, H0, H1, H2, bo, pmax, pamx, psum);
    k_combine<<<(MM + 255) / 256, 256, 0, stream>>>(pmax, pamx, psum, lse,
                                                    out + (size_t)MM * VV);
    dim3 gw(1000, 2);
    k_write_conv<<<gw, 64, 0, stream>>>(Wo, H0, H1, H2, bo, lse, out);
}

// Round 5
// 431.476 us; speedup vs baseline: 1.5284x; 1.0783x over previous
//
#include <hip/hip_runtime.h>
#include <math.h>

#define BB 32     // batch
#define TT 64     // time steps
#define VV 32000  // vocab
#define HH 32     // hidden
#define EE 200    // embedding dim
#define MM (BB * TT)      // 2048 GEMM rows (r = b*TT + t)
#define VC 25             // stats v-chunks
#define VTPC 80           // 16-col v-tiles per chunk (1280 cols)
#define NWE (VV * HH)     // Wo element count
#define WLB ((NWE + 255) / 256)   // 4000 W-limb blocks in k_pre

typedef __attribute__((ext_vector_type(8))) short short8;   // 8 bf16 = 4 VGPR
typedef __attribute__((ext_vector_type(4))) float f32x4;

// x = l0 + l1 + l2 with li bf16 (RNE): combined ~26 mantissa bits >= f32's 24.
__device__ inline void split3(float x, ushort& u0, ushort& u1, ushort& u2) {
    unsigned a = __float_as_uint(x);
    ushort t0 = (ushort)((a + 0x7FFFu + ((a >> 16) & 1u)) >> 16);
    float f0 = __uint_as_float(((unsigned)t0) << 16);
    float r1 = x - f0;
    unsigned b = __float_as_uint(r1);
    ushort t1 = (ushort)((b + 0x7FFFu + ((b >> 16) & 1u)) >> 16);
    float f1 = __uint_as_float(((unsigned)t1) << 16);
    float r2 = r1 - f1;
    unsigned c = __float_as_uint(r2);
    ushort t2 = (ushort)((c + 0x7FFFu + ((c >> 16) & 1u)) >> 16);
    u0 = t0; u1 = t1; u2 = t2;
}

// 6-product bf16x3 MFMA: a*b to ~1e-7 relative. Small terms first.
__device__ inline f32x4 mfma6(short8 a0, short8 a1, short8 a2,
                              short8 b0, short8 b1, short8 b2) {
    f32x4 acc = {0.f, 0.f, 0.f, 0.f};
    acc = __builtin_amdgcn_mfma_f32_16x16x32_bf16(a2, b0, acc, 0, 0, 0);
    acc = __builtin_amdgcn_mfma_f32_16x16x32_bf16(a0, b2, acc, 0, 0, 0);
    acc = __builtin_amdgcn_mfma_f32_16x16x32_bf16(a1, b1, acc, 0, 0, 0);
    acc = __builtin_amdgcn_mfma_f32_16x16x32_bf16(a1, b0, acc, 0, 0, 0);
    acc = __builtin_amdgcn_mfma_f32_16x16x32_bf16(a0, b1, acc, 0, 0, 0);
    acc = __builtin_amdgcn_mfma_f32_16x16x32_bf16(a0, b0, acc, 0, 0, 0);
    return acc;
}

// ---------------- Kernel 1 (fused): i2h GEMV + W-limb split --------------------
// Blocks 0..MM-1: i2h = emb[y] @ Wi.T + bi + bh. Blocks MM..MM+WLB-1: split 256
// Wo elements each into bf16 limbs (stored in the out-region scratch).
__global__ __launch_bounds__(256) void k_pre(
        const int* __restrict__ y, const float* __restrict__ emb,
        const float* __restrict__ Wi, const float* __restrict__ bi,
        const float* __restrict__ bh, const float* __restrict__ Wo,
        float* __restrict__ i2h,
        ushort* __restrict__ W0, ushort* __restrict__ W1, ushort* __restrict__ W2) {
    int blk = blockIdx.x;
    if (blk >= MM) {
        int i = (blk - MM) * 256 + (int)threadIdx.x;
        if (i < NWE) {
            ushort u0, u1, u2; split3(Wo[i], u0, u1, u2);
            W0[i] = u0; W1[i] = u1; W2[i] = u2;
        }
        return;
    }
    int tok = y[blk];
    __shared__ float se[EE];
    for (int e = threadIdx.x; e < EE; e += 256) se[e] = emb[(size_t)tok * EE + e];
    __syncthreads();
    int h = threadIdx.x >> 3;         // 0..31
    int j = threadIdx.x & 7;          // 8 lanes per h
    float acc = 0.f;
    for (int e = j; e < EE; e += 8) acc += se[e] * Wi[h * EE + e];
    acc += __shfl_down(acc, 4, 8);
    acc += __shfl_down(acc, 2, 8);
    acc += __shfl_down(acc, 1, 8);
    if (j == 0) i2h[blk * HH + h] = acc + bi[h] + bh[h];
}

// ---------------- Kernel 2: recurrence, writes H LIMBS directly ----------------
// h_t = tanh(i2h_t + h_{t-1} @ Wh.T); epilogue splits hv into bf16 limbs in
// registers -> no f32 hall array, no separate H-limb pass.
__global__ void k_rnn(const float* __restrict__ enc, const float* __restrict__ Wh,
                      const float* __restrict__ i2h,
                      ushort* __restrict__ H0, ushort* __restrict__ H1,
                      ushort* __restrict__ H2) {
    int b = blockIdx.x;               // 0..31
    int tid = threadIdx.x;            // 64 threads = 1 wave
    __shared__ float hs[HH];
    __shared__ float sWh[HH][HH + 1];
    __shared__ float si[TT * HH];
    for (int i = tid; i < HH * HH; i += 64) sWh[i >> 5][i & 31] = Wh[i];
    for (int i = tid; i < TT * HH; i += 64) si[i] = i2h[b * TT * HH + i];
    if (tid < HH) hs[tid] = enc[b * HH + tid];
    __syncthreads();
    for (int t = 0; t < TT; ++t) {
        float hv = 0.f;
        if (tid < HH) {
            float a0 = si[t * HH + tid], a1 = 0.f, a2 = 0.f, a3 = 0.f;
#pragma unroll
            for (int j = 0; j < HH; j += 4) {
                a0 += sWh[tid][j]     * hs[j];
                a1 += sWh[tid][j + 1] * hs[j + 1];
                a2 += sWh[tid][j + 2] * hs[j + 2];
                a3 += sWh[tid][j + 3] * hs[j + 3];
            }
            hv = tanhf((a0 + a1) + (a2 + a3));
        }
        __syncthreads();
        if (tid < HH) {
            hs[tid] = hv;
            ushort u0, u1, u2; split3(hv, u0, u1, u2);
            int idx = (b * TT + t) * HH + tid;
            H0[idx] = u0; H1[idx] = u1; H2[idx] = u2;
        }
        __syncthreads();
    }
}

// ---------------- Kernel 3: stats via MFMA -------------------------------------
// grid (VC=25, 32), 256 thr = 4 independent waves (no barriers); wave w owns
// M-tile blockIdx.y*4+w. All 4 waves stream the same W-limb tiles -> L1 dedup.
// C/D layout [m89]: col=lane&15 (v), row=(lane>>4)*4+q (m). Stats in 12 VGPRs.
__global__ __launch_bounds__(256) void k_stats_mfma(
        const ushort* __restrict__ W0, const ushort* __restrict__ W1, const ushort* __restrict__ W2,
        const ushort* __restrict__ H0, const ushort* __restrict__ H1, const ushort* __restrict__ H2,
        const float* __restrict__ bo,
        float* __restrict__ pmax, float* __restrict__ pamx, float* __restrict__ psum) {
    int c  = blockIdx.x;
    int wv = threadIdx.x >> 6;
    int l  = threadIdx.x & 63;
    int lc = l & 15, lg = l >> 4;
    int m0 = (blockIdx.y * 4 + wv) * 16;
    size_t aoff = (size_t)(m0 + lc) * HH + lg * 8;
    short8 a0 = *(const short8*)(H0 + aoff);
    short8 a1 = *(const short8*)(H1 + aoff);
    short8 a2 = *(const short8*)(H2 + aoff);

    float mx[4], am[4], sm[4];
#pragma unroll
    for (int q = 0; q < 4; ++q) { mx[q] = -1e30f; am[q] = 0.f; sm[q] = 0.f; }

    int vb = c * (VTPC * 16);         // chunk base column
#pragma unroll 5
    for (int s = 0; s < VTPC; ++s) {
        int v = vb + s * 16 + lc;     // this lane's vocab row in tile s
        size_t boff = (size_t)v * HH + lg * 8;
        short8 b0 = *(const short8*)(W0 + boff);
        short8 b1 = *(const short8*)(W1 + boff);
        short8 b2 = *(const short8*)(W2 + boff);
        f32x4 acc = mfma6(a0, a1, a2, b0, b1, b2);
        float bov = bo[v];
        float vf  = (float)v;
#pragma unroll
        for (int q = 0; q < 4; ++q) {
            float g = acc[q] + bov;
            sm[q] += __expf(g);       // |logit| < ~6: exp w/o max-shift is safe
            if (g > mx[q]) { mx[q] = g; am[q] = vf; }   // strict >: first-occurrence
        }
    }

    // reduce across the 16 lanes (lc bits) sharing the same 4 rows
#pragma unroll
    for (int q = 0; q < 4; ++q) {
#pragma unroll
        for (int msk = 1; msk <= 8; msk <<= 1) {
            float m2 = __shfl_xor(mx[q], msk);
            float av = __shfl_xor(am[q], msk);
            float s2 = __shfl_xor(sm[q], msk);
            sm[q] += s2;
            if (m2 > mx[q] || (m2 == mx[q] && av < am[q])) { mx[q] = m2; am[q] = av; }
        }
    }
    if (lc == 0) {
        int base = c * MM + m0 + lg * 4;
#pragma unroll
        for (int q = 0; q < 4; ++q) {
            pmax[base + q] = mx[q];
            pamx[base + q] = am[q];
            psum[base + q] = sm[q];
        }
    }
}

// ---------------- Kernel 4: combine partials -> lse, preds ---------------------
__global__ void k_combine(const float* __restrict__ pmax, const float* __restrict__ pamx,
                          const float* __restrict__ psum,
                          float* __restrict__ lse, float* __restrict__ preds) {
    int r = blockIdx.x * blockDim.x + threadIdx.x;   // r = b*TT + t
    if (r >= MM) return;
    float m = -1e30f, a = 0.f, s = 0.f;
    for (int c = 0; c < VC; ++c) {
        int idx = c * MM + r;
        float m2 = pmax[idx], a2 = pamx[idx];
        s += psum[idx];
        if (m2 > m || (m2 == m && a2 < a)) { m = m2; a = a2; }
    }
    lse[r] = logf(s);
    preds[r] = a;    // preds[b][t] (r = b*TT+t), index as float (exact to 2^24)
}

// ---------------- Kernel 5: logits via MFMA, on-the-fly W conversion -----------
// grid (1000, 4), 1 wave. Block owns 32 vocab cols: converts those 32 Wo rows to
// limb frags ONCE in registers (independent of the out-region limbs -> no race
// with overwriting them), then loops 32 M-tiles. Same split3+mfma6 as stats =>
// bit-identical logits. lse slice staged in LDS (2 KB) to keep the hot loop free
// of L2-latency scalar loads. Stores: 4 x 64-B segments / instr, pairs merge to
// full 128-B lines. Roofline: the 262 MB output write.
__global__ __launch_bounds__(64) void k_write_conv(
        const float* __restrict__ Wo,
        const ushort* __restrict__ H0, const ushort* __restrict__ H1, const ushort* __restrict__ H2,
        const float* __restrict__ bo, const float* __restrict__ lse,
        float* __restrict__ out) {
    int v0 = blockIdx.x * 32;
    int lc = threadIdx.x & 15, lg = threadIdx.x >> 4;
    int mbase = blockIdx.y * (MM / 4);          // 512 rows per block

    __shared__ float sl[MM / 4];
    for (int i = threadIdx.x; i < MM / 4; i += 64) sl[i] = lse[mbase + i];

    short8 b0a, b1a, b2a, b0b, b1b, b2b;
    {
        const float* ra = Wo + (size_t)(v0 + lc) * HH + lg * 8;
        const float* rb = ra + 16 * HH;
#pragma unroll
        for (int j = 0; j < 8; ++j) {
            ushort u0, u1, u2; split3(ra[j], u0, u1, u2);
            b0a[j] = (short)u0; b1a[j] = (short)u1; b2a[j] = (short)u2;
        }
#pragma unroll
        for (int j = 0; j < 8; ++j) {
            ushort u0, u1, u2; split3(rb[j], u0, u1, u2);
            b0b[j] = (short)u0; b1b[j] = (short)u1; b2b[j] = (short)u2;
        }
    }
    float boA = bo[v0 + lc], boB = bo[v0 + 16 + lc];
    __syncthreads();

    for (int s = 0; s < MM / 4 / 16; ++s) {     // 32 M-tiles
        int m0 = mbase + s * 16;
        size_t aoff = (size_t)(m0 + lc) * HH + lg * 8;
        short8 a0 = *(const short8*)(H0 + aoff);
        short8 a1 = *(const short8*)(H1 + aoff);
        short8 a2 = *(const short8*)(H2 + aoff);
        f32x4 accA = mfma6(a0, a1, a2, b0a, b1a, b2a);
        f32x4 accB = mfma6(a0, a1, a2, b0b, b1b, b2b);
        int row = m0 + lg * 4;
        int lrow = s * 16 + lg * 4;
#pragma unroll
        for (int q = 0; q < 4; ++q) {
            float ls = sl[lrow + q];
            size_t ob = (size_t)(row + q) * VV + v0 + lc;
            out[ob]      = accA[q] + boA - ls;
            out[ob + 16] = accB[q] + boB - ls;
        }
    }
}

// ---------------- Launch -------------------------------------------------------
extern "C" void kernel_launch(void* const* d_in, const int* in_sizes, int n_in,
                              void* d_out, int out_size, void* d_ws, size_t ws_size,
                              hipStream_t stream) {
    const int*   y   = (const int*)  d_in[0];
    const float* enc = (const float*)d_in[1];
    const float* emb = (const float*)d_in[2];
    const float* Wi  = (const float*)d_in[3];
    const float* bi  = (const float*)d_in[4];
    const float* Wh  = (const float*)d_in[5];
    const float* bh  = (const float*)d_in[6];
    const float* Wo  = (const float*)d_in[7];
    const float* bo  = (const float*)d_in[8];
    float* out = (float*)d_out;
    float* ws  = (float*)d_ws;

    // workspace (floats) — total 319,488 floats = 1.278 MB (ws>=~7MB crashed in
    // round 3; <=1.32 MB is proven safe — hard constraint).
    float* i2h  = ws;                        // 65,536
    ushort* H0  = (ushort*)(ws + 65536);     // 3 x 65,536 ushorts = 98,304 floats
    ushort* H1  = H0 + MM * HH;
    ushort* H2  = H1 + MM * HH;
    float* pmax = ws + 163840;               // VC*MM = 51,200
    float* pamx = ws + 215040;               // 51,200
    float* psum = ws + 266240;               // 51,200
    float* lse  = ws + 317440;               // 2,048

    // W limbs: scratch inside the (not-yet-written) logprobs output region.
    ushort* W0 = (ushort*)out;               // 3 x 1,024,000 ushorts = 6.1 MB
    ushort* W1 = W0 + NWE;
    ushort* W2 = W1 + NWE;

    k_pre<<<MM + WLB, 256, 0, stream>>>(y, emb, Wi, bi, bh, Wo, i2h, W0, W1, W2);
    k_rnn<<<BB, 64, 0, stream>>>(enc, Wh, i2h, H0, H1, H2);
    dim3 gs(VC, 32);
    k_stats_mfma<<<gs, 256, 0, stream>>>(W0, W1, W2, H0, H1, H2, bo, pmax, pamx, psum);
    k_combine<<<(MM + 255) / 256, 256, 0, stream>>>(pmax, pamx, psum, lse,
                                                    out + (size_t)MM * VV);
    dim3 gw(1000, 4);
    k_write_conv<<<gw, 64, 0, stream>>>(Wo, H0, H1, H2, bo, lse, out);
}